// Round 3
// baseline (6866.862 us; speedup 1.0000x reference)
//
#include <hip/hip_runtime.h>
#include <hip/hip_bf16.h>
#include <cstdint>
#include <cstddef>

// ---------------------------------------------------------------------------
// RANNet: 2-layer recurrent additive network, B=128 S=2048 D=H=256, fc head.
// Round 3:
//  - rec: 16 WGs x 8 batch rows (M=8 inside 16-row MFMA tile, rows 8-15 zero)
//    -> halves per-CU preact traffic, doubles CUs pulling the stream.
//  - preacts: f/i in bf16 (pre-scaled by -log2 e), xp in f32. 64 B/lane/step.
//  - GEMM-0 reads fp32 x directly (convert folded into staging).
// ---------------------------------------------------------------------------

typedef __bf16 bf16;
typedef __bf16 bf16x8 __attribute__((ext_vector_type(8)));
typedef __bf16 bf16x4 __attribute__((ext_vector_type(4)));
typedef float  floatx4 __attribute__((ext_vector_type(4)));

#define B_   128
#define S_   2048
#define H_   256
#define NEG_LOG2E -1.442695040888963f

// preP layout (bytes), per layer:
//   step t stride   : 262144  (= 128 rows * (512*2 + 256*4))
//   (wg*8+wv) block : 2048    (wg = b>>3, wv = wave owning cols 32*wv..+32)
//   lane v block    : 64      (v = (row&7)>>2 *16 + (col&15), row=b&7)
//   inner           : [f bf16x8 nt*4+r | i bf16x8 | xp f32x4 nt=0 | xp f32x4 nt=1]
//                      0..15             16..31     32..47          48..63

// ---------------------------------------------------------------------------
__global__ void prep_weights(
    const float* __restrict__ Wf0, const float* __restrict__ Wi0, const float* __restrict__ Wx0,
    const float* __restrict__ Wf1, const float* __restrict__ Wi1, const float* __restrict__ Wx1,
    const float* __restrict__ Uf0, const float* __restrict__ Ui0,
    const float* __restrict__ Uf1, const float* __restrict__ Ui1,
    const float* __restrict__ bf0, const float* __restrict__ bi0, const float* __restrict__ bx0,
    const float* __restrict__ bf1, const float* __restrict__ bi1, const float* __restrict__ bx1,
    const float* __restrict__ fcW,
    bf16* __restrict__ W0cat, bf16* __restrict__ W1cat,
    bf16* __restrict__ U0cat, bf16* __restrict__ U1cat,
    float* __restrict__ b0cat, float* __restrict__ b1cat, float* __restrict__ fcWT)
{
    int tid = blockIdx.x * blockDim.x + threadIdx.x;
    int nth = gridDim.x * blockDim.x;
    for (int idx = tid; idx < 768 * 256; idx += nth) {
        int r = idx >> 8, k = idx & 255, rr = r & 255;
        const float* s0 = (r < 256) ? Wf0 : ((r < 512) ? Wi0 : Wx0);
        const float* s1 = (r < 256) ? Wf1 : ((r < 512) ? Wi1 : Wx1);
        W0cat[idx] = (bf16)s0[rr * 256 + k];
        W1cat[idx] = (bf16)s1[rr * 256 + k];
    }
    for (int idx = tid; idx < 512 * 256; idx += nth) {
        int r = idx >> 8, k = idx & 255, rr = r & 255;
        U0cat[idx] = (bf16)((r < 256 ? Uf0 : Ui0)[rr * 256 + k]);
        U1cat[idx] = (bf16)((r < 256 ? Uf1 : Ui1)[rr * 256 + k]);
    }
    for (int idx = tid; idx < 768; idx += nth) {
        const float* s0 = (idx < 256) ? bf0 : ((idx < 512) ? bi0 : bx0);
        const float* s1 = (idx < 256) ? bf1 : ((idx < 512) ? bi1 : bx1);
        b0cat[idx] = s0[idx & 255];
        b1cat[idx] = s1[idx & 255];
    }
    for (int idx = tid; idx < 256 * 256; idx += nth) {
        int h = idx >> 8, o = idx & 255;
        fcWT[idx] = fcW[o * 256 + h];   // fcWT[h][o]
    }
}

// ---------------------------------------------------------------------------
// Pre-activation GEMM, 128x128 tile, BK=32. L0: A = fp32 x (converted in
// staging). L1: A = bf16 h1b. Epilogue scatters into rec-fragment layout.
// ---------------------------------------------------------------------------
template<int L0>
__global__ __launch_bounds__(256) void gemm_preact(
    const float* __restrict__ X, const bf16* __restrict__ Ab,
    const bf16* __restrict__ W, const float* __restrict__ bias,
    char* __restrict__ preP, int t0g)
{
    __shared__ bf16 At[128 * 32];   // [row][k] 64B rows
    __shared__ bf16 Bt[128 * 32];
    int t  = blockIdx.x;            // 128 rows == one timestep (chunk-local)
    int n0 = blockIdx.y * 128;
    int tid = threadIdx.x;
    int lane = tid & 63, wave = tid >> 6;
    int wm = (wave >> 1) * 64, wn = (wave & 1) * 64;
    int qm = lane & 15, qk = lane >> 4;
    floatx4 acc[4][4] = {};

    for (int k0 = 0; k0 < 256; k0 += 32) {
#pragma unroll
        for (int j = 0; j < 2; ++j) {
            int c = tid * 2 + j;            // 16B chunk id
            int row = c >> 2, kc = c & 3;
            bf16x8 av;
            if (L0) {
                const float* src = X + ((size_t)row * S_ + t0g + t) * 256 + k0 + kc * 8;
                floatx4 v0 = *(const floatx4*)src;
                floatx4 v1 = *(const floatx4*)(src + 4);
#pragma unroll
                for (int u = 0; u < 4; ++u) { av[u] = (bf16)v0[u]; av[4 + u] = (bf16)v1[u]; }
            } else {
                av = *(const bf16x8*)(Ab + (size_t)(t * 128 + row) * 256 + k0 + kc * 8);
            }
            *(bf16x8*)(At + c * 8) = av;
            *(bf16x8*)(Bt + c * 8) = *(const bf16x8*)(W + (size_t)(n0 + row) * 256 + k0 + kc * 8);
        }
        __syncthreads();
        bf16x8 af[4], bfr[4];
#pragma unroll
        for (int i = 0; i < 4; ++i) {
            af[i]  = *(const bf16x8*)(At + (wm + i * 16 + qm) * 32 + qk * 8);
            bfr[i] = *(const bf16x8*)(Bt + (wn + i * 16 + qm) * 32 + qk * 8);
        }
#pragma unroll
        for (int mi = 0; mi < 4; ++mi)
#pragma unroll
            for (int ni = 0; ni < 4; ++ni)
                acc[mi][ni] = __builtin_amdgcn_mfma_f32_16x16x32_bf16(af[mi], bfr[ni], acc[mi][ni], 0, 0, 0);
        __syncthreads();
    }
    // epilogue: scatter into rec-fragment layout
    char* base = preP + (size_t)t * 262144;
#pragma unroll
    for (int mi = 0; mi < 4; ++mi) {
        int mb  = wm + mi * 16 + qk * 4;      // batch row b (plus r)
        int wg  = mb >> 3;
        int qk2 = (mb >> 2) & 1;              // (b&7)>>2
#pragma unroll
        for (int ni = 0; ni < 4; ++ni) {
            int c = n0 + wn + ni * 16 + qm;
            int g = c >> 8, ch = c & 255;
            int wv = ch >> 5, nt = (ch >> 4) & 1, qmc = ch & 15;
            int v = qk2 * 16 + qmc;
            char* dst = base + (size_t)((wg * 8 + wv) * 2048) + v * 64;
            float bb = bias[c];
            if (g < 2) {                       // f or i: bf16, pre-scaled
                bf16x4 o;
#pragma unroll
                for (int r = 0; r < 4; ++r)
                    o[r] = (bf16)(NEG_LOG2E * (acc[mi][ni][r] + bb));
                *(bf16x4*)(dst + g * 16 + nt * 8) = o;
            } else {                           // xp: f32
                floatx4 o;
#pragma unroll
                for (int r = 0; r < 4; ++r) o[r] = acc[mi][ni][r] + bb;
                *(floatx4*)(dst + 32 + nt * 16) = o;
            }
        }
    }
}

// ---------------------------------------------------------------------------
// Recurrence: 16 WGs x 8 batch rows, 512 thr (8 waves). Wave w owns h-cols
// [32w,32w+32) and computes both gates. LDS h tile is 16 rows (MFMA shape);
// rows 8-15 are zero forever. Valid lanes = lane<32 (qk<2).
// One __syncthreads per step; depth-1 double-buffered preact prefetch.
// ---------------------------------------------------------------------------
__global__ __launch_bounds__(512) void rec_layer(
    const char* __restrict__ preP,   // see layout at top
    bf16* __restrict__ hout,         // [T][128][256] bf16, or nullptr
    const bf16* __restrict__ Ucat,   // [512][256] = [Uf;Ui]
    float* __restrict__ hstate,      // [128][256] in/out
    int T)
{
    __shared__ bf16 hb[2][16 * 264];     // [buf][row][256+8pad]
    const int tid = threadIdx.x, lane = tid & 63, wave = tid >> 6;
    const int qm = lane & 15, qk = lane >> 4;
    const int wg = blockIdx.x, bbase = wg * 8, cb = wave * 32;
    const bool valid = (lane < 32);

    // stationary U fragments (B-operand layout)
    bf16x8 Ufr[2][8], Uir[2][8];
#pragma unroll
    for (int nt = 0; nt < 2; ++nt)
#pragma unroll
        for (int kt = 0; kt < 8; ++kt) {
            Ufr[nt][kt] = *(const bf16x8*)(Ucat + (size_t)(cb + nt * 16 + qm) * 256 + kt * 32 + qk * 8);
            Uir[nt][kt] = *(const bf16x8*)(Ucat + (size_t)(256 + cb + nt * 16 + qm) * 256 + kt * 32 + qk * 8);
        }
    {   // init LDS h: rows 0-7 from state, rows 8-15 zero; zero both buffers
        int row = tid >> 5, c8 = (tid & 31) * 8;
        bf16x8 z = {};
        bf16x8 v = z;
        if (row < 8) {
            const float* hs = hstate + (size_t)(bbase + row) * 256 + c8;
#pragma unroll
            for (int j = 0; j < 8; ++j) v[j] = (bf16)hs[j];
        }
        *(bf16x8*)(hb[0] + row * 264 + c8) = v;
        *(bf16x8*)(hb[1] + row * 264 + c8) = z;
    }
    float hm[2][4] = {};
    if (valid) {
#pragma unroll
        for (int nt = 0; nt < 2; ++nt)
#pragma unroll
            for (int r = 0; r < 4; ++r)
                hm[nt][r] = hstate[(size_t)(bbase + qk * 4 + r) * 256 + cb + nt * 16 + qm];
    }
    __syncthreads();

    const char* pw = preP + (size_t)(wg * 8 + wave) * 2048 + (size_t)(lane & 31) * 64;
#define PLD(F, I, X0, X1, tt) { const char* p_ = pw + (size_t)(tt) * 262144;    \
        F  = *(const bf16x8*)(p_);       I  = *(const bf16x8*)(p_ + 16);        \
        X0 = *(const floatx4*)(p_ + 32); X1 = *(const floatx4*)(p_ + 48); }

    bf16x8 fA, iA, fB, iB; floatx4 xA0, xA1, xB0, xB1;
    if (valid) PLD(fA, iA, xA0, xA1, 0);
    int cur = 0;

    auto step = [&](int t, int curb, bf16x8& F, bf16x8& I, floatx4& X0, floatx4& X1) {
        floatx4 accf[2] = {}, acci[2] = {};
        const bf16* hc = hb[curb];
#pragma unroll
        for (int kt = 0; kt < 8; ++kt) {
            bf16x8 a = *(const bf16x8*)(hc + qm * 264 + kt * 32 + qk * 8);
            accf[0] = __builtin_amdgcn_mfma_f32_16x16x32_bf16(a, Ufr[0][kt], accf[0], 0, 0, 0);
            accf[1] = __builtin_amdgcn_mfma_f32_16x16x32_bf16(a, Ufr[1][kt], accf[1], 0, 0, 0);
            acci[0] = __builtin_amdgcn_mfma_f32_16x16x32_bf16(a, Uir[0][kt], acci[0], 0, 0, 0);
            acci[1] = __builtin_amdgcn_mfma_f32_16x16x32_bf16(a, Uir[1][kt], acci[1], 0, 0, 0);
        }
        bf16* hn = hb[curb ^ 1];
        if (valid) {
#pragma unroll
            for (int nt = 0; nt < 2; ++nt)
#pragma unroll
                for (int r = 0; r < 4; ++r) {
                    float pf = (float)F[nt * 4 + r];
                    float pi = (float)I[nt * 4 + r];
                    float px = nt ? X1[r] : X0[r];
                    float ef = fminf(fmaf(accf[nt][r], NEG_LOG2E, pf), 80.0f);
                    float ei = fminf(fmaf(acci[nt][r], NEG_LOG2E, pi), 80.0f);
                    float A1 = 1.0f + __builtin_amdgcn_exp2f(ef);
                    float B1 = 1.0f + __builtin_amdgcn_exp2f(ei);
                    float N  = fmaf(hm[nt][r], B1, px * A1);
                    float h  = N * __builtin_amdgcn_rcpf(A1 * B1);
                    hm[nt][r] = h;
                    hn[(qk * 4 + r) * 264 + cb + nt * 16 + qm] = (bf16)h;
                }
        }
        __syncthreads();
        if (hout && tid < 256) {
            int row = tid >> 5, c8 = (tid & 31) * 8;
            bf16x8 v = *(const bf16x8*)(hn + row * 264 + c8);
            *(bf16x8*)(hout + ((size_t)t * 128 + bbase + row) * 256 + c8) = v;
        }
    };

    for (int t = 0; t < T; t += 2) {
        if (valid) PLD(fB, iB, xB0, xB1, t + 1);
        step(t, cur, fA, iA, xA0, xA1);  cur ^= 1;
        int t2 = (t + 2 < T) ? t + 2 : 0;          // dummy safe reload on last
        if (valid) PLD(fA, iA, xA0, xA1, t2);
        step(t + 1, cur, fB, iB, xB0, xB1); cur ^= 1;
    }
#undef PLD
    if (valid) {
#pragma unroll
        for (int nt = 0; nt < 2; ++nt)
#pragma unroll
            for (int r = 0; r < 4; ++r)
                hstate[(size_t)(bbase + qk * 4 + r) * 256 + cb + nt * 16 + qm] = hm[nt][r];
    }
}

// ---------------------------------------------------------------------------
__global__ void fc_head(const float* __restrict__ h2, const float* __restrict__ fcWT,
                        const float* __restrict__ fcb, float* __restrict__ out)
{
    int b = blockIdx.x, o = threadIdx.x;
    __shared__ float hrow[256];
    hrow[o] = h2[(size_t)b * 256 + o];
    __syncthreads();
    float acc = fcb[o];
#pragma unroll 8
    for (int h = 0; h < 256; ++h)
        acc = fmaf(hrow[h], fcWT[h * 256 + o], acc);
    out[(size_t)b * 256 + o] = acc;
}

// ---------------------------------------------------------------------------
extern "C" void kernel_launch(void* const* d_in, const int* in_sizes, int n_in,
                              void* d_out, int out_size, void* d_ws, size_t ws_size,
                              hipStream_t stream)
{
    (void)in_sizes; (void)n_in; (void)out_size;
    const float* x   = (const float*)d_in[0];
    const float* Wf0 = (const float*)d_in[1];
    const float* bf0 = (const float*)d_in[2];
    const float* Uf0 = (const float*)d_in[3];
    const float* Wi0 = (const float*)d_in[4];
    const float* bi0 = (const float*)d_in[5];
    const float* Ui0 = (const float*)d_in[6];
    const float* Wx0 = (const float*)d_in[7];
    const float* bx0 = (const float*)d_in[8];
    const float* Wf1 = (const float*)d_in[9];
    const float* bf1 = (const float*)d_in[10];
    const float* Uf1 = (const float*)d_in[11];
    const float* Wi1 = (const float*)d_in[12];
    const float* bi1 = (const float*)d_in[13];
    const float* Ui1 = (const float*)d_in[14];
    const float* Wx1 = (const float*)d_in[15];
    const float* bx1 = (const float*)d_in[16];
    const float* fcW = (const float*)d_in[17];
    const float* fcb = (const float*)d_in[18];

    char* p = (char*)d_ws;
    auto alloc = [&](size_t bytes) -> char* {
        char* r = p; p += (bytes + 255) & ~(size_t)255; return r;
    };
    bf16*  W0cat = (bf16*)alloc(768 * 256 * 2);
    bf16*  W1cat = (bf16*)alloc(768 * 256 * 2);
    bf16*  U0cat = (bf16*)alloc(512 * 256 * 2);
    bf16*  U1cat = (bf16*)alloc(512 * 256 * 2);
    float* b0cat = (float*)alloc(768 * 4);
    float* b1cat = (float*)alloc(768 * 4);
    float* fcWT  = (float*)alloc(256 * 256 * 4);
    float* h0s   = (float*)alloc(128 * 256 * 4);
    float* h1s   = (float*)alloc(128 * 256 * 4);
    size_t fixed = (size_t)(p - (char*)d_ws);

    // per-chunk bytes: pre0 T*262144 + h1b T*65536 + pre1 T*262144 = T*589824
    int T_c = 2048;
    while (T_c > 32 && fixed + (size_t)T_c * 589824 + 4096 > ws_size) T_c >>= 1;
    char* pre0 = alloc((size_t)T_c * 262144);
    bf16* h1b  = (bf16*)alloc((size_t)T_c * 65536);
    char* pre1 = alloc((size_t)T_c * 262144);

    hipMemsetAsync(h0s, 0, 128 * 256 * 4, stream);
    hipMemsetAsync(h1s, 0, 128 * 256 * 4, stream);

    prep_weights<<<512, 256, 0, stream>>>(Wf0, Wi0, Wx0, Wf1, Wi1, Wx1,
                                          Uf0, Ui0, Uf1, Ui1,
                                          bf0, bi0, bx0, bf1, bi1, bx1, fcW,
                                          W0cat, W1cat, U0cat, U1cat, b0cat, b1cat, fcWT);

    int NC = S_ / T_c;
    for (int c = 0; c < NC; ++c) {
        int t0 = c * T_c;
        gemm_preact<1><<<dim3(T_c, 6), 256, 0, stream>>>(x, nullptr, W0cat, b0cat, pre0, t0);
        rec_layer<<<16, 512, 0, stream>>>(pre0, h1b, U0cat, h0s, T_c);
        gemm_preact<0><<<dim3(T_c, 6), 256, 0, stream>>>(nullptr, h1b, W1cat, b1cat, pre1, 0);
        rec_layer<<<16, 512, 0, stream>>>(pre1, nullptr, U1cat, h1s, T_c);
    }
    fc_head<<<128, 256, 0, stream>>>(h1s, fcWT, fcb, (float*)d_out);
}